// Round 4
// baseline (698.987 us; speedup 1.0000x reference)
//
#include <hip/hip_runtime.h>
#include <math.h>

// Problem constants (reference: N_NODES=50000, F_in=1433, F1=16, F2=7)
#define F_IN 1433
#define F1 16
#define F2 7
#define SCAN_CHUNK 2048
#define NREP 8          // atomic-contention replication factor
#define NSEG1 4         // split-K segments for GEMM1
#define KSEG1 384       // K per segment (4*384 = 1536 >= 1433), 6 x 64-lane slices

// ---------------- init (zeros replicated counters) ----------------
__global__ void k_init_cnt(int* __restrict__ cnt_r, int n) {
    int i = blockIdx.x * 256 + threadIdx.x;
    if (i < n) cnt_r[i] = 0;
}

// ---------------- degree count, 8-way replicated ----------------
__global__ void k_count(const int* __restrict__ edges, int* __restrict__ cnt_r,
                        int E, int N) {
    int e = blockIdx.x * 256 + threadIdx.x;
    if (e < E) atomicAdd(&cnt_r[(blockIdx.x & (NREP - 1)) * N + edges[E + e]], 1);
}

// ---------------- scan (3-phase exclusive prefix over summed cnt -> rs) ------
__global__ void k_scan1(const int* __restrict__ cnt_r, int* __restrict__ rs,
                        int* __restrict__ bsum, int N) {
    __shared__ int sh[256];
    int tid = threadIdx.x;
    int base = blockIdx.x * SCAN_CHUNK + tid * 8;
    int v[8];
    int s = 0;
#pragma unroll
    for (int u = 0; u < 8; ++u) {
        int idx = base + u;
        int t = 0;
        if (idx < N) {
#pragma unroll
            for (int r = 0; r < NREP; ++r) t += cnt_r[r * N + idx];
        }
        v[u] = t;
        s += t;
    }
    sh[tid] = s;
    __syncthreads();
    for (int off = 1; off < 256; off <<= 1) {
        int y = 0;
        if (tid >= off) y = sh[tid - off];
        __syncthreads();
        sh[tid] += y;
        __syncthreads();
    }
    int run = sh[tid] - s;
#pragma unroll
    for (int u = 0; u < 8; ++u) {
        int idx = base + u;
        if (idx < N) rs[idx] = run;
        run += v[u];
    }
    if (tid == 255) bsum[blockIdx.x] = sh[255];
}

__global__ void k_scan2(const int* __restrict__ bsum, int* __restrict__ boff, int NB) {
    if (blockIdx.x == 0 && threadIdx.x == 0) {
        int r = 0;
        for (int b = 0; b < NB; ++b) { int t = bsum[b]; boff[b] = r; r += t; }
    }
}

// finalize rs, build per-replica cursors, total cnt, dinv
__global__ void k_scan3(int* __restrict__ rs, int* __restrict__ cursor_r,
                        const int* __restrict__ cnt_r, int* __restrict__ cnt,
                        float* __restrict__ dinv, const int* __restrict__ boff, int N) {
    int i = blockIdx.x * 256 + threadIdx.x;
    if (i < N) {
        int run = rs[i] + boff[i / SCAN_CHUNK];
        rs[i] = run;
        int total = 0;
#pragma unroll
        for (int r = 0; r < NREP; ++r) {
            cursor_r[r * N + i] = run;
            int c = cnt_r[r * N + i];
            run += c;
            total += c;
        }
        cnt[i] = total;
        dinv[i] = rsqrtf((float)total + 1.0f);   // +1 self loop
    }
}

// ---------------- CSR fill (replica matches k_count's: same e -> same block) -
__global__ void k_fill(const int* __restrict__ edges, int* __restrict__ cursor_r,
                       int* __restrict__ col, int E, int N) {
    int e = blockIdx.x * 256 + threadIdx.x;
    if (e < E) {
        int d = edges[E + e];
        int s = edges[e];
        int pos = atomicAdd(&cursor_r[(blockIdx.x & (NREP - 1)) * N + d], 1);
        col[pos] = s;
    }
}

// ---------------- GEMM1: K-sliced-across-lanes GEMV --------------------------
// Lane l owns k-slice {k0 + l + 64t, t=0..5}; its 96 W values live in VGPRs
// (loaded once per block -> ZERO W traffic in the loop; kills the scalar-load
// lgkmcnt stalls of the row-per-lane layout). x-loads are 4B dwords, perfectly
// coalesced across lanes. Per row-pair: 192 FMAs then a 5-step select-butterfly
// (32 values: 2 rows x 16 features; value index == sub-lane id) reduces across
// lanes. Triple-buffered row-pair prefetch keeps ~2 pairs in flight.
template <int S>
__device__ __forceinline__ void bstep(float b[32], int sub) {
#pragma unroll
    for (int m = 0; m < S; ++m) {
        bool up = (sub & S) != 0;
        float keep = up ? b[m + S] : b[m];
        float send = up ? b[m] : b[m + S];
        b[m] = keep + __shfl_xor(send, S, 64);
    }
}

__device__ __forceinline__ void load_pair(const float* __restrict__ x, int row0,
                                          int kl, int N, float xc0[6], float xc1[6]) {
    const float* p0 = x + (long)row0 * F_IN + kl;
#pragma unroll
    for (int t = 0; t < 6; ++t) {
        int k = kl + 64 * t;
        bool kk = k < F_IN;
        xc0[t] = (kk && row0 < N)     ? p0[64 * t]        : 0.f;
        xc1[t] = (kk && row0 + 1 < N) ? p0[F_IN + 64 * t] : 0.f;
    }
}

__device__ __forceinline__ void comp_pair(const float wreg[6][16],
                                          const float xc0[6], const float xc1[6],
                                          int row0, int sub, int lane,
                                          long segbase, int N,
                                          float* __restrict__ gpart) {
    float b[32];
#pragma unroll
    for (int j = 0; j < 16; ++j) {
        b[j]      = xc0[0] * wreg[0][j];
        b[16 + j] = xc1[0] * wreg[0][j];
    }
#pragma unroll
    for (int t = 1; t < 6; ++t) {
#pragma unroll
        for (int j = 0; j < 16; ++j) {
            b[j]      = fmaf(xc0[t], wreg[t][j], b[j]);
            b[16 + j] = fmaf(xc1[t], wreg[t][j], b[16 + j]);
        }
    }
    // fold lanes l and l^32 (lanes 32..63 become replicas)
#pragma unroll
    for (int m = 0; m < 32; ++m) b[m] += __shfl_xor(b[m], 32, 64);
    bstep<16>(b, sub);
    bstep<8>(b, sub);
    bstep<4>(b, sub);
    bstep<2>(b, sub);
    bstep<1>(b, sub);
    // lane sub (0..31) now holds combined index sub: row = row0+(sub>>4), f = sub&15
    if (lane < 32) {
        int row = row0 + (sub >> 4);
        if (row < N) gpart[segbase + (long)row * 16 + (sub & 15)] = b[0];
    }
}

__global__ __launch_bounds__(64) void k_gemv1(const float* __restrict__ x,
                                              const float* __restrict__ W,
                                              float* __restrict__ gpart, int N) {
    const int lane = threadIdx.x;
    const int seg  = blockIdx.y;
    const int k0   = seg * KSEG1;
    const int r0   = blockIdx.x * 64;          // 64 rows (32 pairs) per block
    const int kl   = k0 + lane;
    const int sub  = lane & 31;
    const long segbase = (long)seg * N * 16;

    // per-lane W slice -> VGPRs (once per block)
    float wreg[6][16];
#pragma unroll
    for (int t = 0; t < 6; ++t) {
        int k = kl + 64 * t;
        if (k < F_IN) {
            const float4* wr = (const float4*)(W + (long)k * 16);
            float4 a = wr[0], b4 = wr[1], c = wr[2], d = wr[3];
            wreg[t][0]  = a.x;  wreg[t][1]  = a.y;  wreg[t][2]  = a.z;  wreg[t][3]  = a.w;
            wreg[t][4]  = b4.x; wreg[t][5]  = b4.y; wreg[t][6]  = b4.z; wreg[t][7]  = b4.w;
            wreg[t][8]  = c.x;  wreg[t][9]  = c.y;  wreg[t][10] = c.z;  wreg[t][11] = c.w;
            wreg[t][12] = d.x;  wreg[t][13] = d.y;  wreg[t][14] = d.z;  wreg[t][15] = d.w;
        } else {
#pragma unroll
            for (int j = 0; j < 16; ++j) wreg[t][j] = 0.f;
        }
    }

    float A0[6], A1[6], B0[6], B1[6], C0[6], C1[6];
    load_pair(x, r0 + 0, kl, N, A0, A1);
    load_pair(x, r0 + 2, kl, N, B0, B1);
    load_pair(x, r0 + 4, kl, N, C0, C1);

#pragma unroll 1
    for (int p = 0; p < 30; p += 3) {
        comp_pair(wreg, A0, A1, r0 + 2 * p, sub, lane, segbase, N, gpart);
        if (p + 3 < 32) load_pair(x, r0 + 2 * (p + 3), kl, N, A0, A1);
        comp_pair(wreg, B0, B1, r0 + 2 * (p + 1), sub, lane, segbase, N, gpart);
        if (p + 4 < 32) load_pair(x, r0 + 2 * (p + 4), kl, N, B0, B1);
        comp_pair(wreg, C0, C1, r0 + 2 * (p + 2), sub, lane, segbase, N, gpart);
        if (p + 5 < 32) load_pair(x, r0 + 2 * (p + 5), kl, N, C0, C1);
    }
    comp_pair(wreg, A0, A1, r0 + 60, sub, lane, segbase, N, gpart);
    comp_pair(wreg, B0, B1, r0 + 62, sub, lane, segbase, N, gpart);
}

// ---------------- reduce partials: g = dinv[row] * sum_seg gpart -------------
__global__ __launch_bounds__(256) void k_greduce(const float* __restrict__ gpart,
                                                 const float* __restrict__ dinv,
                                                 float* __restrict__ g, int N, int nseg) {
    int i4 = blockIdx.x * 256 + threadIdx.x;
    if (i4 >= N * 4) return;
    const float4* gp = (const float4*)gpart;
    float4 s = gp[i4];
    for (int p = 1; p < nseg; ++p) {
        float4 t = gp[(long)p * N * 4 + i4];
        s.x += t.x; s.y += t.y; s.z += t.z; s.w += t.w;
    }
    float d = dinv[i4 >> 2];
    s.x *= d; s.y *= d; s.z *= d; s.w *= d;
    ((float4*)g)[i4] = s;
}

// ---------------- gather layer1: x1 = relu(dinv*(sum g[src] + g[self]) + b1) --
__global__ __launch_bounds__(256) void k_gather1(const int* __restrict__ col,
                                                 const int* __restrict__ rs,
                                                 const int* __restrict__ cnt,
                                                 const float* __restrict__ g,
                                                 const float* __restrict__ dinv,
                                                 const float* __restrict__ b1,
                                                 float* __restrict__ x1, int N) {
    int node = blockIdx.x * 4 + (threadIdx.x >> 6);
    if (node >= N) return;
    int lane = threadIdx.x & 63;
    int q = lane >> 4;   // neighbor slot 0..3
    int j = lane & 15;   // feature
    int start = rs[node];
    int c = cnt[node];
    float acc = 0.f;
    int p = q;
    if (p < c) {
        int s = col[start + p];
        for (;;) {
            int pn = p + 4;
            bool more = pn < c;
            int sn = 0;
            if (more) sn = col[start + pn];      // prefetch next index
            acc += g[(long)s * F1 + j];
            if (!more) break;
            s = sn; p = pn;
        }
    }
    acc += __shfl_down(acc, 32, 64);
    acc += __shfl_down(acc, 16, 64);
    if (lane < 16) {
        float v = dinv[node] * (acc + g[(long)node * F1 + j]) + b1[j];
        x1[(long)node * F1 + j] = fmaxf(v, 0.f);
    }
}

// ---------------- GEMM2: g2 = dinv * (x1 @ W2), padded to 8 cols -------------
__global__ __launch_bounds__(256) void k_gemm2(const float* __restrict__ x1,
                                               const float* __restrict__ W2,
                                               const float* __restrict__ dinv,
                                               float* __restrict__ g2, int N) {
    int i = blockIdx.x * 256 + threadIdx.x;
    if (i >= N) return;
    const float4* xr = (const float4*)(x1 + (long)i * F1);
    float4 a0 = xr[0], a1 = xr[1], a2 = xr[2], a3 = xr[3];
    float xv[F1] = {a0.x, a0.y, a0.z, a0.w, a1.x, a1.y, a1.z, a1.w,
                    a2.x, a2.y, a2.z, a2.w, a3.x, a3.y, a3.z, a3.w};
    float acc[F2];
#pragma unroll
    for (int j = 0; j < F2; ++j) acc[j] = 0.f;
#pragma unroll
    for (int k = 0; k < F1; ++k) {
#pragma unroll
        for (int j = 0; j < F2; ++j) acc[j] = fmaf(xv[k], W2[k * F2 + j], acc[j]);
    }
    float d = dinv[i];
    float4* out = (float4*)(g2 + (long)i * 8);
    out[0] = make_float4(d * acc[0], d * acc[1], d * acc[2], d * acc[3]);
    out[1] = make_float4(d * acc[4], d * acc[5], d * acc[6], 0.f);
}

// ---------------- gather layer2 + bias + log_softmax -> d_out ----------------
__global__ __launch_bounds__(256) void k_gather2(const int* __restrict__ col,
                                                 const int* __restrict__ rs,
                                                 const int* __restrict__ cnt,
                                                 const float* __restrict__ g2,
                                                 const float* __restrict__ dinv,
                                                 const float* __restrict__ b2,
                                                 float* __restrict__ out, int N) {
    int node = blockIdx.x * 4 + (threadIdx.x >> 6);
    if (node >= N) return;
    int lane = threadIdx.x & 63;
    int q = lane >> 3;  // neighbor slot 0..7
    int j = lane & 7;   // feature 0..7 (7 = pad)
    int start = rs[node];
    int c = cnt[node];
    float acc = 0.f;
    int p = q;
    if (p < c) {
        int s = col[start + p];
        for (;;) {
            int pn = p + 8;
            bool more = pn < c;
            int sn = 0;
            if (more) sn = col[start + pn];      // prefetch next index
            acc += g2[(long)s * 8 + j];
            if (!more) break;
            s = sn; p = pn;
        }
    }
    acc += __shfl_down(acc, 32, 64);
    acc += __shfl_down(acc, 16, 64);
    acc += __shfl_down(acc, 8, 64);
    if (lane < 8) {
        float vv = -INFINITY;
        if (j < F2)
            vv = dinv[node] * (acc + g2[(long)node * 8 + j]) + b2[j];
        float m = vv;
        m = fmaxf(m, __shfl_xor(m, 1, 64));
        m = fmaxf(m, __shfl_xor(m, 2, 64));
        m = fmaxf(m, __shfl_xor(m, 4, 64));
        float e = (j < F2) ? expf(vv - m) : 0.f;
        e += __shfl_xor(e, 1, 64);
        e += __shfl_xor(e, 2, 64);
        e += __shfl_xor(e, 4, 64);
        if (j < F2)
            out[(long)node * F2 + j] = vv - m - logf(e);
    }
}

extern "C" void kernel_launch(void* const* d_in, const int* in_sizes, int n_in,
                              void* d_out, int out_size, void* d_ws, size_t ws_size,
                              hipStream_t stream) {
    const float* x     = (const float*)d_in[0];
    const int*   edges = (const int*)d_in[1];
    const float* W1    = (const float*)d_in[2];
    const float* b1    = (const float*)d_in[3];
    const float* W2    = (const float*)d_in[4];
    const float* b2    = (const float*)d_in[5];
    float* outp = (float*)d_out;

    int N = in_sizes[0] / F_IN;       // 50000
    int E = in_sizes[1] / 2;          // 1600000
    int NB = (N + SCAN_CHUNK - 1) / SCAN_CHUNK;

    char* ws = (char*)d_ws;
    size_t o = 0;
    auto alloc = [&](size_t bytes) { size_t r = o; o += (bytes + 255) & ~(size_t)255; return r; };
    int*   cnt_r    = (int*)  (ws + alloc((size_t)NREP * N * 4));
    int*   cursor_r = (int*)  (ws + alloc((size_t)NREP * N * 4));
    int*   cnt      = (int*)  (ws + alloc((size_t)N * 4));
    int*   rs       = (int*)  (ws + alloc((size_t)N * 4));
    float* dinv     = (float*)(ws + alloc((size_t)N * 4));
    int*   bsum     = (int*)  (ws + alloc((size_t)NB * 4));
    int*   boff     = (int*)  (ws + alloc((size_t)NB * 4));
    int*   col      = (int*)  (ws + alloc((size_t)E * 4));
    float* g        = (float*)(ws + alloc((size_t)N * F1 * 4));
    float* x1       = (float*)(ws + alloc((size_t)N * F1 * 4));
    float* g2       = (float*)(ws + alloc((size_t)N * 8 * 4));
    float* gpart    = (float*)(ws + alloc((size_t)NSEG1 * N * F1 * 4));
    (void)n_in; (void)out_size; (void)ws_size;

    int gN256 = (N + 255) / 256;
    int gE256 = (E + 255) / 256;

    k_init_cnt<<<(NREP * N + 255) / 256, 256, 0, stream>>>(cnt_r, NREP * N);
    k_count<<<gE256, 256, 0, stream>>>(edges, cnt_r, E, N);
    k_scan1<<<NB, 256, 0, stream>>>(cnt_r, rs, bsum, N);
    k_scan2<<<1, 64, 0, stream>>>(bsum, boff, NB);
    k_scan3<<<gN256, 256, 0, stream>>>(rs, cursor_r, cnt_r, cnt, dinv, boff, N);
    k_fill<<<gE256, 256, 0, stream>>>(edges, cursor_r, col, E, N);

    // GEMM1: 1-wave blocks, 64 rows (32 pairs) per block, 4 K-segments
    int RB = (N + 63) / 64;
    dim3 g1(RB, NSEG1);
    k_gemv1<<<g1, 64, 0, stream>>>(x, W1, gpart, N);
    k_greduce<<<(N * 4 + 255) / 256, 256, 0, stream>>>(gpart, dinv, g, N, NSEG1);
    k_gather1<<<(N + 3) / 4, 256, 0, stream>>>(col, rs, cnt, g, dinv, b1, x1, N);
    k_gemm2<<<gN256, 256, 0, stream>>>(x1, W2, dinv, g2, N);
    k_gather2<<<(N + 3) / 4, 256, 0, stream>>>(col, rs, cnt, g2, dinv, b2, outp, N);
}